// Round 21
// baseline (728.563 us; speedup 1.0000x reference)
//
#include <hip/hip_runtime.h>

typedef __attribute__((ext_vector_type(4))) float f32x4;
typedef __attribute__((ext_vector_type(8))) __bf16 bf16x8;
typedef unsigned short u16;

#define GAS(p) ((const __attribute__((address_space(1))) void*)(p))
#define LAS(p) ((__attribute__((address_space(3))) void*)(p))

__device__ __forceinline__ u16 f32_to_bf16(float f) {
  unsigned u = __builtin_bit_cast(unsigned, f);
  u += 0x7FFFu + ((u >> 16) & 1u);
  return (u16)(u >> 16);
}

// ---------------- elementwise f32 -> bf16 ----------------
__global__ __launch_bounds__(256) void k_convert(const float* __restrict__ X,
                                                 u16* __restrict__ Y, int n4) {
  int i = blockIdx.x * 256 + threadIdx.x;
  if (i >= n4) return;
  float4 v = ((const float4*)X)[i];
  ushort4 r;
  r.x = f32_to_bf16(v.x); r.y = f32_to_bf16(v.y);
  r.z = f32_to_bf16(v.z); r.w = f32_to_bf16(v.w);
  ((ushort4*)Y)[i] = r;
}

// ---------------- W [K][N] f32 -> WT [N][K] bf16 ----------------
__global__ __launch_bounds__(256) void k_transpose_w(const float* __restrict__ W,
                                                     u16* __restrict__ WT,
                                                     int K, int N) {
  __shared__ float tile[32][33];
  int n0 = blockIdx.x * 32, k0 = blockIdx.y * 32;
  int tx = threadIdx.x & 31, ty = threadIdx.x >> 5;
#pragma unroll
  for (int r = 0; r < 4; ++r)
    tile[ty + r * 8][tx] = W[(long)(k0 + ty + r * 8) * N + n0 + tx];
  __syncthreads();
#pragma unroll
  for (int r = 0; r < 4; ++r)
    WT[(long)(n0 + ty + r * 8) * K + k0 + tx] = f32_to_bf16(tile[tx][ty + r * 8]);
}

// ---------------- V [BH][S][128] bf16 -> VT [BH][128][S] bf16 ----------------
__global__ __launch_bounds__(256) void k_transpose_v(const u16* __restrict__ V,
                                                     u16* __restrict__ VT) {
  __shared__ u16 tile[32][34];
  int s0 = blockIdx.x * 32, d0 = blockIdx.y * 32, bh = blockIdx.z;
  int tx = threadIdx.x & 31, ty = threadIdx.x >> 5;
  const u16* Vb = V + (long)bh * 2048 * 128;
  u16* VTb = VT + (long)bh * 128 * 2048;
#pragma unroll
  for (int r = 0; r < 4; ++r)
    tile[ty + r * 8][tx] = Vb[(long)(s0 + ty + r * 8) * 128 + d0 + tx];
  __syncthreads();
#pragma unroll
  for (int r = 0; r < 4; ++r)
    VTb[(long)(d0 + ty + r * 8) * 2048 + s0 + tx] = tile[tx][ty + r * 8];
}

// ===== 128x128 bf16 GEMM, BK=32, 2 LDS buffers, 4 waves, 5 BLOCKS/CU =====
// R21: push the residency lever (the only lever that won all session:
// R14 1->3 blocks/CU = +33%) to its LDS limit. 2 buffers x 16 KB = 32 KB
// -> 5 blocks/CU (20 waves/CU; VGPR 5x68=340 <= 512/SIMD). The cost vs
// R15's 3-buffer: stage(t+1) must issue AFTER the barrier (WAR: buf^1's
// last readers ran compute(t-1) before this barrier), so the per-tile
// wait is vmcnt(0) with one compute phase (~570 cy) of lead — the exact
// m97 pattern (874-912 TF at only 3 blocks/CU); residual drain covered
// by 4 other resident blocks (m114). Swizzle involution (R15, conflicts
// measured 0), setprio, XCD-bijective grid swizzle unchanged.
template <int EPI>
__global__ __launch_bounds__(256, 5) void k_gemm(
    const u16* __restrict__ A, const u16* __restrict__ BT,
    const float* __restrict__ bias,
    u16* __restrict__ Qo, u16* __restrict__ Ko, u16* __restrict__ Vo,
    float* __restrict__ Cout, int M, int N, int K) {
  __shared__ alignas(16) u16 AS[2][128 * 32];  // 2 x 8 KB
  __shared__ alignas(16) u16 BS[2][128 * 32];  // 2 x 8 KB
  const int wave = threadIdx.x >> 6, lane = threadIdx.x & 63;
  const int wr = wave >> 1, wc = wave & 1;
  const int l15 = lane & 15, l4 = lane >> 4;
  // staging: 1KB chunk = 16 rows x 32 cols; lane -> row lane>>2, slot lane&3;
  // source slot pre-XORed with (row>>1)&3 (proven involution: 64B rows ->
  // start-bank (16*row+4*slot)%32; key (row>>1)&3 -> 2 lanes/bank = free).
  const int srow = lane >> 2;
  const int sslot = (lane & 3) ^ ((srow >> 1) & 3);

  const int nwg = gridDim.x;  // 1536 / 512, both % 8 == 0
  const int swz = ((int)blockIdx.x & 7) * (nwg >> 3) + ((int)blockIdx.x >> 3);
  const int mt = M >> 7;
  const int bm = swz % mt, bn = swz / mt;
  const int brow = bm * 128, bcol = bn * 128;
  const int NT = K >> 5;

  const u16* aBase = A + (long)(brow + wave * 16 + srow) * K + sslot * 8;
  const u16* bBase = BT + (long)(bcol + wave * 16 + srow) * K + sslot * 8;
  const long K64 = (long)K * 64;  // 64-row advance

  auto stage = [&](int t, int buf) {  // 4 global_load_lds dwordx4 / thread
    const long t32 = (long)t * 32;
    __builtin_amdgcn_global_load_lds(GAS(aBase + t32),
                                     LAS(&AS[buf][wave * 512]), 16, 0, 0);
    __builtin_amdgcn_global_load_lds(GAS(aBase + t32 + K64),
                                     LAS(&AS[buf][(wave + 4) * 512]), 16, 0, 0);
    __builtin_amdgcn_global_load_lds(GAS(bBase + t32),
                                     LAS(&BS[buf][wave * 512]), 16, 0, 0);
    __builtin_amdgcn_global_load_lds(GAS(bBase + t32 + K64),
                                     LAS(&BS[buf][(wave + 4) * 512]), 16, 0, 0);
  };

  const f32x4 fzero = {0.f, 0.f, 0.f, 0.f};
  f32x4 acc[4][4];
#pragma unroll
  for (int m = 0; m < 4; ++m)
#pragma unroll
    for (int n = 0; n < 4; ++n) acc[m][n] = fzero;

  const int rkey = (l15 >> 1) & 3;  // read-side XOR key: (row>>1)&3 per lane
  auto compute = [&](int buf) {
    const u16* Ac = &AS[buf][0];
    const u16* Bc = &BS[buf][0];
    bf16x8 afr[4], bfr[4];
#pragma unroll
    for (int f = 0; f < 4; ++f) {
      const int Ra = wr * 64 + f * 16 + l15;
      afr[f] = *(const bf16x8*)(Ac + Ra * 32 + ((l4 ^ rkey) * 8));
      const int Rb = wc * 64 + f * 16 + l15;
      bfr[f] = *(const bf16x8*)(Bc + Rb * 32 + ((l4 ^ rkey) * 8));
    }
    __builtin_amdgcn_s_setprio(1);
#pragma unroll
    for (int m = 0; m < 4; ++m)
#pragma unroll
      for (int n = 0; n < 4; ++n)
        acc[m][n] = __builtin_amdgcn_mfma_f32_16x16x32_bf16(afr[m], bfr[n],
                                                            acc[m][n], 0, 0, 0);
    __builtin_amdgcn_s_setprio(0);
  };

  stage(0, 0);
  int bufc = 0;
  for (int t = 0; t < NT; ++t) {
    asm volatile("s_waitcnt vmcnt(0)" ::: "memory");  // tile t landed
    __builtin_amdgcn_s_barrier();
    if (t + 1 < NT) stage(t + 1, bufc ^ 1);  // buf^1 readers done pre-barrier
    compute(bufc);
    bufc ^= 1;
  }

  if (EPI == 0) {
    // 128-col tiles never straddle the 2048 Q/K/V boundaries
    const int which = bcol >> 11;
    u16* dst = (which == 0) ? Qo : (which == 1) ? Ko : Vo;
    const int cbase = bcol & 2047;
#pragma unroll
    for (int n = 0; n < 4; ++n) {
      const int col = cbase + wc * 64 + n * 16 + l15;
      const int h = col >> 7, d = col & 127;
      const float bv = bias[bcol + wc * 64 + n * 16 + l15];
#pragma unroll
      for (int m = 0; m < 4; ++m) {
#pragma unroll
        for (int r = 0; r < 4; ++r) {
          const int row = brow + wr * 64 + m * 16 + l4 * 4 + r;  // b*2048+s
          const int bb = row >> 11, s = row & 2047;
          dst[(((long)(bb * 16 + h)) * 2048 + s) * 128 + d] =
              f32_to_bf16(acc[m][n][r] + bv);
        }
      }
    }
  } else {
#pragma unroll
    for (int m = 0; m < 4; ++m)
#pragma unroll
      for (int r = 0; r < 4; ++r) {
        const int row = brow + wr * 64 + m * 16 + l4 * 4 + r;
#pragma unroll
        for (int n = 0; n < 4; ++n) {
          const int col = bcol + wc * 64 + n * 16 + l15;
          Cout[(long)row * N + col] = acc[m][n][r] + bias[col];
        }
      }
  }
}

// ---------------- flash attention with ALiBi, causal ----------------
// R7 form, EXACT — best-measured attention (~75 us). Refuted alternatives:
// 8-wave shared staging (R17/R18), single-buffered 4-block residency (R19).
__global__ __launch_bounds__(256, 4) void k_attn(const u16* __restrict__ Q,
                                                 const u16* __restrict__ Kp,
                                                 const u16* __restrict__ VT,
                                                 u16* __restrict__ Oa) {
  __shared__ alignas(16) u16 Kl[2][64 * 128];
  __shared__ alignas(16) u16 Vl[2][128 * 64];
  __shared__ alignas(16) u16 Pl[4][16 * 64];
  const int b = blockIdx.x;
  const int bh = b & 31;
  const int qt = 31 - (b >> 5);  // heavy-first LPT
  const int bb = bh >> 4, h = bh & 15;
  const int wave = threadIdx.x >> 6, lane = threadIdx.x & 63;
  const int l15 = lane & 15, l4 = lane >> 4;
  const int l7 = lane & 7, l8 = lane >> 3;
  const float LOG2E = 1.4426950408889634f;
  const float scale = 0.08838834764831845f * LOG2E;
  const float slope = exp2f(-0.5f * (float)h) * LOG2E;

  const int q0 = qt * 64 + wave * 16;
  const u16* Qb = Q + ((long)bh * 2048 + q0 + l15) * 128;
  bf16x8 qf[4];
#pragma unroll
  for (int kk = 0; kk < 4; ++kk) qf[kk] = *(const bf16x8*)(Qb + kk * 32 + l4 * 8);

  const u16* Kb = Kp + (long)bh * 2048 * 128;
  const u16* VTb = VT + (long)bh * 128 * 2048;

  auto stageK = [&](int jt, int buf) {
#pragma unroll
    for (int g = 0; g < 4; ++g) {
      const int wcc = g * 4 + wave;
      const int row = wcc * 4 + l4;
      const u16* src = Kb + (long)(jt * 64 + row) * 128 + ((l15 ^ (row & 7)) * 8);
      __builtin_amdgcn_global_load_lds(GAS(src), LAS(&Kl[buf][wcc * 512]), 16, 0, 0);
    }
  };
  auto stageV = [&](int jt, int buf) {
#pragma unroll
    for (int g = 0; g < 4; ++g) {
      const int wcc = g * 4 + wave;
      const int d = wcc * 8 + l8;
      const u16* src = VTb + (long)d * 2048 + jt * 64 + ((l7 ^ l8) * 8);
      __builtin_amdgcn_global_load_lds(GAS(src), LAS(&Vl[buf][wcc * 512]), 16, 0, 0);
    }
  };

  float rs[4];
  f32x4 O[8];
  const f32x4 fzero = {0.f, 0.f, 0.f, 0.f};
#pragma unroll
  for (int r = 0; r < 4; ++r) rs[r] = 0.f;
#pragma unroll
  for (int nb = 0; nb < 8; ++nb) O[nb] = fzero;

  u16* Pw = Pl[wave];
  const int irow = q0 + l4 * 4;
  const int sw = l15 & 7;

  stageK(0, 0);
  stageV(0, 0);
  __syncthreads();

  for (int jt = 0; jt <= qt; ++jt) {
    const int cur = jt & 1;
    if (jt < qt) {
      stageK(jt + 1, cur ^ 1);
      stageV(jt + 1, cur ^ 1);
    }
    const u16* Kc = Kl[cur];
    const u16* Vc = Vl[cur];
    const int j0 = jt * 64;
#pragma unroll
    for (int cb = 0; cb < 4; ++cb) {
      f32x4 sa = fzero;
      const u16* kp = Kc + (cb * 16 + l15) * 128;
#pragma unroll
      for (int kk = 0; kk < 4; ++kk) {
        bf16x8 kf = *(const bf16x8*)(kp + (((kk * 4 + l4) ^ sw) * 8));
        sa = __builtin_amdgcn_mfma_f32_16x16x32_bf16(qf[kk], kf, sa, 0, 0, 0);
      }
      const int j = j0 + cb * 16 + l15;
#pragma unroll
      for (int r = 0; r < 4; ++r) {
        int i = irow + r;
        float s = sa[r] * scale - slope * (float)(i - j);
        float p = __builtin_amdgcn_exp2f((j <= i) ? s : -1e30f);
        rs[r] += p;
        int rloc = l4 * 4 + r;
        int cbyte = (cb * 16 + l15) * 2;
        *(u16*)((char*)Pw + rloc * 128 + (cbyte ^ ((rloc & 7) << 4))) =
            f32_to_bf16(p);
      }
    }
    bf16x8 pf0 = *(const bf16x8*)((char*)Pw + l15 * 128 +
                                  ((l4 * 16) ^ ((l15 & 7) << 4)));
    bf16x8 pf1 = *(const bf16x8*)((char*)Pw + l15 * 128 +
                                  ((64 + l4 * 16) ^ ((l15 & 7) << 4)));
#pragma unroll
    for (int nb = 0; nb < 8; ++nb) {
      const u16* vp = Vc + (nb * 16 + l15) * 64;
      bf16x8 v0 = *(const bf16x8*)(vp + ((l4 ^ sw) * 8));
      bf16x8 v1 = *(const bf16x8*)(vp + (((4 + l4) ^ sw) * 8));
      O[nb] = __builtin_amdgcn_mfma_f32_16x16x32_bf16(pf0, v0, O[nb], 0, 0, 0);
      O[nb] = __builtin_amdgcn_mfma_f32_16x16x32_bf16(pf1, v1, O[nb], 0, 0, 0);
    }
    __syncthreads();
  }
#pragma unroll
  for (int r = 0; r < 4; ++r) {
    float v = rs[r];
    v += __shfl_xor(v, 1);
    v += __shfl_xor(v, 2);
    v += __shfl_xor(v, 4);
    v += __shfl_xor(v, 8);
    float inv = 1.f / v;
    int i = irow + r;
    u16* op = Oa + ((long)bb * 2048 + i) * 2048 + h * 128;
#pragma unroll
    for (int nb = 0; nb < 8; ++nb) op[nb * 16 + l15] = f32_to_bf16(O[nb][r] * inv);
  }
}

extern "C" void kernel_launch(void* const* d_in, const int* in_sizes, int n_in,
                              void* d_out, int out_size, void* d_ws, size_t ws_size,
                              hipStream_t stream) {
  const float* x = (const float*)d_in[0];
  const float* Wqkv = (const float*)d_in[1];
  const float* bqkv = (const float*)d_in[2];
  const float* Wo = (const float*)d_in[3];
  const float* bo = (const float*)d_in[4];
  float* out = (float*)d_out;

  char* ws = (char*)d_ws;
  u16* xb = (u16*)(ws);
  u16* VTb = (u16*)(ws);  // aliases xb (xb dead after GEMM1)
  u16* WqkvT = (u16*)(ws + 16777216);
  u16* attn_out = (u16*)(ws + 16777216);  // aliases WqkvT (dead after GEMM1)
  u16* WoT = (u16*)(ws + 16777216 + 25165824);
  u16* Qb = (u16*)(ws + 50331648);
  u16* Kb = (u16*)(ws + 67108864);
  u16* Vb = (u16*)(ws + 83886080);

  k_convert<<<8192, 256, 0, stream>>>(x, xb, 8388608 / 4);
  k_transpose_w<<<dim3(192, 64), 256, 0, stream>>>(Wqkv, WqkvT, 2048, 6144);
  k_transpose_w<<<dim3(64, 64), 256, 0, stream>>>(Wo, WoT, 2048, 2048);
  // GEMM1: 128^2 tiles -> 32 x 48 = 1536 blocks (6/CU work, 5 resident/CU)
  k_gemm<0><<<dim3(1536), 256, 0, stream>>>(xb, WqkvT, bqkv, Qb, Kb, Vb,
                                            nullptr, 4096, 6144, 2048);
  k_transpose_v<<<dim3(64, 4, 32), 256, 0, stream>>>(Vb, VTb);
  // attn: 1024 blocks x 4 waves, double-buffered K/V, heavy-first LPT
  k_attn<<<dim3(1024), 256, 0, stream>>>(Qb, Kb, VTb, attn_out);
  // GEMM2: 128^2 tiles -> 32 x 16 = 512 blocks (2/CU work, all resident)
  k_gemm<1><<<dim3(512), 256, 0, stream>>>(attn_out, WoT, bo, nullptr,
                                           nullptr, nullptr, out, 4096, 2048,
                                           2048);
}

// Round 22
// 280.429 us; speedup vs baseline: 2.5980x; 2.5980x over previous
//
#include <hip/hip_runtime.h>

typedef __attribute__((ext_vector_type(4))) float f32x4;
typedef __attribute__((ext_vector_type(8))) __bf16 bf16x8;
typedef unsigned short u16;

#define GAS(p) ((const __attribute__((address_space(1))) void*)(p))
#define LAS(p) ((__attribute__((address_space(3))) void*)(p))

__device__ __forceinline__ u16 f32_to_bf16(float f) {
  unsigned u = __builtin_bit_cast(unsigned, f);
  u += 0x7FFFu + ((u >> 16) & 1u);
  return (u16)(u >> 16);
}

// ---------------- elementwise f32 -> bf16 ----------------
__global__ __launch_bounds__(256) void k_convert(const float* __restrict__ X,
                                                 u16* __restrict__ Y, int n4) {
  int i = blockIdx.x * 256 + threadIdx.x;
  if (i >= n4) return;
  float4 v = ((const float4*)X)[i];
  ushort4 r;
  r.x = f32_to_bf16(v.x); r.y = f32_to_bf16(v.y);
  r.z = f32_to_bf16(v.z); r.w = f32_to_bf16(v.w);
  ((ushort4*)Y)[i] = r;
}

// ---------------- W [K][N] f32 -> WT [N][K] bf16 ----------------
__global__ __launch_bounds__(256) void k_transpose_w(const float* __restrict__ W,
                                                     u16* __restrict__ WT,
                                                     int K, int N) {
  __shared__ float tile[32][33];
  int n0 = blockIdx.x * 32, k0 = blockIdx.y * 32;
  int tx = threadIdx.x & 31, ty = threadIdx.x >> 5;
#pragma unroll
  for (int r = 0; r < 4; ++r)
    tile[ty + r * 8][tx] = W[(long)(k0 + ty + r * 8) * N + n0 + tx];
  __syncthreads();
#pragma unroll
  for (int r = 0; r < 4; ++r)
    WT[(long)(n0 + ty + r * 8) * K + k0 + tx] = f32_to_bf16(tile[tx][ty + r * 8]);
}

// ---------------- V [BH][S][128] bf16 -> VT [BH][128][S] bf16 ----------------
__global__ __launch_bounds__(256) void k_transpose_v(const u16* __restrict__ V,
                                                     u16* __restrict__ VT) {
  __shared__ u16 tile[32][34];
  int s0 = blockIdx.x * 32, d0 = blockIdx.y * 32, bh = blockIdx.z;
  int tx = threadIdx.x & 31, ty = threadIdx.x >> 5;
  const u16* Vb = V + (long)bh * 2048 * 128;
  u16* VTb = VT + (long)bh * 128 * 2048;
#pragma unroll
  for (int r = 0; r < 4; ++r)
    tile[ty + r * 8][tx] = Vb[(long)(s0 + ty + r * 8) * 128 + d0 + tx];
  __syncthreads();
#pragma unroll
  for (int r = 0; r < 4; ++r)
    VTb[(long)(d0 + ty + r * 8) * 2048 + s0 + tx] = tile[tx][ty + r * 8];
}

// ===== 128x128 bf16 GEMM, BK=32, 2 LDS buffers, 4 waves, 4 BLOCKS/CU =====
// R22: R21's 2-buffer stage-after-barrier scheme at the FEASIBLE bound.
// R21's (256,5) set VGPR cap 96 < ~120 live -> catastrophic spill (VGPR
// forced to 48, FETCH 650 MB). (256,4) caps at 128 > live: no spill, and
// LDS 32 KB gives 4 resident blocks (vs R15's 3). Per tile: {vmcnt(0) ->
// barrier -> stage(t+1, buf^1) -> compute(buf)} — m97's exposed-drain
// semantics (874-912 TF at only 3 blocks), covered here by 3 other blocks.
// WAR-safe: buf^1's last readers ran compute(t-1) before this barrier.
// RAW-safe: vmcnt(0)+barrier makes stage(t) visible to all waves.
// Swizzle involution (R15, conflicts 0), setprio, XCD swizzle unchanged.
template <int EPI>
__global__ __launch_bounds__(256, 4) void k_gemm(
    const u16* __restrict__ A, const u16* __restrict__ BT,
    const float* __restrict__ bias,
    u16* __restrict__ Qo, u16* __restrict__ Ko, u16* __restrict__ Vo,
    float* __restrict__ Cout, int M, int N, int K) {
  __shared__ alignas(16) u16 AS[2][128 * 32];  // 2 x 8 KB
  __shared__ alignas(16) u16 BS[2][128 * 32];  // 2 x 8 KB
  const int wave = threadIdx.x >> 6, lane = threadIdx.x & 63;
  const int wr = wave >> 1, wc = wave & 1;
  const int l15 = lane & 15, l4 = lane >> 4;
  // staging: 1KB chunk = 16 rows x 32 cols; lane -> row lane>>2, slot lane&3;
  // source slot pre-XORed with (row>>1)&3 (proven involution: 64B rows ->
  // start-bank (16*row+4*slot)%32; key (row>>1)&3 -> 2 lanes/bank = free).
  const int srow = lane >> 2;
  const int sslot = (lane & 3) ^ ((srow >> 1) & 3);

  const int nwg = gridDim.x;  // 1536 / 512, both % 8 == 0
  const int swz = ((int)blockIdx.x & 7) * (nwg >> 3) + ((int)blockIdx.x >> 3);
  const int mt = M >> 7;
  const int bm = swz % mt, bn = swz / mt;
  const int brow = bm * 128, bcol = bn * 128;
  const int NT = K >> 5;

  const u16* aBase = A + (long)(brow + wave * 16 + srow) * K + sslot * 8;
  const u16* bBase = BT + (long)(bcol + wave * 16 + srow) * K + sslot * 8;
  const long K64 = (long)K * 64;  // 64-row advance

  auto stage = [&](int t, int buf) {  // 4 global_load_lds dwordx4 / thread
    const long t32 = (long)t * 32;
    __builtin_amdgcn_global_load_lds(GAS(aBase + t32),
                                     LAS(&AS[buf][wave * 512]), 16, 0, 0);
    __builtin_amdgcn_global_load_lds(GAS(aBase + t32 + K64),
                                     LAS(&AS[buf][(wave + 4) * 512]), 16, 0, 0);
    __builtin_amdgcn_global_load_lds(GAS(bBase + t32),
                                     LAS(&BS[buf][wave * 512]), 16, 0, 0);
    __builtin_amdgcn_global_load_lds(GAS(bBase + t32 + K64),
                                     LAS(&BS[buf][(wave + 4) * 512]), 16, 0, 0);
  };

  const f32x4 fzero = {0.f, 0.f, 0.f, 0.f};
  f32x4 acc[4][4];
#pragma unroll
  for (int m = 0; m < 4; ++m)
#pragma unroll
    for (int n = 0; n < 4; ++n) acc[m][n] = fzero;

  const int rkey = (l15 >> 1) & 3;  // read-side XOR key: (row>>1)&3 per lane
  auto compute = [&](int buf) {
    const u16* Ac = &AS[buf][0];
    const u16* Bc = &BS[buf][0];
    bf16x8 afr[4], bfr[4];
#pragma unroll
    for (int f = 0; f < 4; ++f) {
      const int Ra = wr * 64 + f * 16 + l15;
      afr[f] = *(const bf16x8*)(Ac + Ra * 32 + ((l4 ^ rkey) * 8));
      const int Rb = wc * 64 + f * 16 + l15;
      bfr[f] = *(const bf16x8*)(Bc + Rb * 32 + ((l4 ^ rkey) * 8));
    }
    __builtin_amdgcn_s_setprio(1);
#pragma unroll
    for (int m = 0; m < 4; ++m)
#pragma unroll
      for (int n = 0; n < 4; ++n)
        acc[m][n] = __builtin_amdgcn_mfma_f32_16x16x32_bf16(afr[m], bfr[n],
                                                            acc[m][n], 0, 0, 0);
    __builtin_amdgcn_s_setprio(0);
  };

  stage(0, 0);
  int bufc = 0;
  for (int t = 0; t < NT; ++t) {
    asm volatile("s_waitcnt vmcnt(0)" ::: "memory");  // tile t landed
    __builtin_amdgcn_s_barrier();
    if (t + 1 < NT) stage(t + 1, bufc ^ 1);  // buf^1 readers done pre-barrier
    compute(bufc);
    bufc ^= 1;
  }

  if (EPI == 0) {
    // 128-col tiles never straddle the 2048 Q/K/V boundaries
    const int which = bcol >> 11;
    u16* dst = (which == 0) ? Qo : (which == 1) ? Ko : Vo;
    const int cbase = bcol & 2047;
#pragma unroll
    for (int n = 0; n < 4; ++n) {
      const int col = cbase + wc * 64 + n * 16 + l15;
      const int h = col >> 7, d = col & 127;
      const float bv = bias[bcol + wc * 64 + n * 16 + l15];
#pragma unroll
      for (int m = 0; m < 4; ++m) {
#pragma unroll
        for (int r = 0; r < 4; ++r) {
          const int row = brow + wr * 64 + m * 16 + l4 * 4 + r;  // b*2048+s
          const int bb = row >> 11, s = row & 2047;
          dst[(((long)(bb * 16 + h)) * 2048 + s) * 128 + d] =
              f32_to_bf16(acc[m][n][r] + bv);
        }
      }
    }
  } else {
#pragma unroll
    for (int m = 0; m < 4; ++m)
#pragma unroll
      for (int r = 0; r < 4; ++r) {
        const int row = brow + wr * 64 + m * 16 + l4 * 4 + r;
#pragma unroll
        for (int n = 0; n < 4; ++n) {
          const int col = bcol + wc * 64 + n * 16 + l15;
          Cout[(long)row * N + col] = acc[m][n][r] + bias[col];
        }
      }
  }
}

// ---------------- flash attention with ALiBi, causal ----------------
// R7 form, EXACT — best-measured attention (~75 us). Refuted alternatives:
// 8-wave shared staging (R17/R18), single-buffered 4-block residency (R19).
__global__ __launch_bounds__(256, 4) void k_attn(const u16* __restrict__ Q,
                                                 const u16* __restrict__ Kp,
                                                 const u16* __restrict__ VT,
                                                 u16* __restrict__ Oa) {
  __shared__ alignas(16) u16 Kl[2][64 * 128];
  __shared__ alignas(16) u16 Vl[2][128 * 64];
  __shared__ alignas(16) u16 Pl[4][16 * 64];
  const int b = blockIdx.x;
  const int bh = b & 31;
  const int qt = 31 - (b >> 5);  // heavy-first LPT
  const int bb = bh >> 4, h = bh & 15;
  const int wave = threadIdx.x >> 6, lane = threadIdx.x & 63;
  const int l15 = lane & 15, l4 = lane >> 4;
  const int l7 = lane & 7, l8 = lane >> 3;
  const float LOG2E = 1.4426950408889634f;
  const float scale = 0.08838834764831845f * LOG2E;
  const float slope = exp2f(-0.5f * (float)h) * LOG2E;

  const int q0 = qt * 64 + wave * 16;
  const u16* Qb = Q + ((long)bh * 2048 + q0 + l15) * 128;
  bf16x8 qf[4];
#pragma unroll
  for (int kk = 0; kk < 4; ++kk) qf[kk] = *(const bf16x8*)(Qb + kk * 32 + l4 * 8);

  const u16* Kb = Kp + (long)bh * 2048 * 128;
  const u16* VTb = VT + (long)bh * 128 * 2048;

  auto stageK = [&](int jt, int buf) {
#pragma unroll
    for (int g = 0; g < 4; ++g) {
      const int wcc = g * 4 + wave;
      const int row = wcc * 4 + l4;
      const u16* src = Kb + (long)(jt * 64 + row) * 128 + ((l15 ^ (row & 7)) * 8);
      __builtin_amdgcn_global_load_lds(GAS(src), LAS(&Kl[buf][wcc * 512]), 16, 0, 0);
    }
  };
  auto stageV = [&](int jt, int buf) {
#pragma unroll
    for (int g = 0; g < 4; ++g) {
      const int wcc = g * 4 + wave;
      const int d = wcc * 8 + l8;
      const u16* src = VTb + (long)d * 2048 + jt * 64 + ((l7 ^ l8) * 8);
      __builtin_amdgcn_global_load_lds(GAS(src), LAS(&Vl[buf][wcc * 512]), 16, 0, 0);
    }
  };

  float rs[4];
  f32x4 O[8];
  const f32x4 fzero = {0.f, 0.f, 0.f, 0.f};
#pragma unroll
  for (int r = 0; r < 4; ++r) rs[r] = 0.f;
#pragma unroll
  for (int nb = 0; nb < 8; ++nb) O[nb] = fzero;

  u16* Pw = Pl[wave];
  const int irow = q0 + l4 * 4;
  const int sw = l15 & 7;

  stageK(0, 0);
  stageV(0, 0);
  __syncthreads();

  for (int jt = 0; jt <= qt; ++jt) {
    const int cur = jt & 1;
    if (jt < qt) {
      stageK(jt + 1, cur ^ 1);
      stageV(jt + 1, cur ^ 1);
    }
    const u16* Kc = Kl[cur];
    const u16* Vc = Vl[cur];
    const int j0 = jt * 64;
#pragma unroll
    for (int cb = 0; cb < 4; ++cb) {
      f32x4 sa = fzero;
      const u16* kp = Kc + (cb * 16 + l15) * 128;
#pragma unroll
      for (int kk = 0; kk < 4; ++kk) {
        bf16x8 kf = *(const bf16x8*)(kp + (((kk * 4 + l4) ^ sw) * 8));
        sa = __builtin_amdgcn_mfma_f32_16x16x32_bf16(qf[kk], kf, sa, 0, 0, 0);
      }
      const int j = j0 + cb * 16 + l15;
#pragma unroll
      for (int r = 0; r < 4; ++r) {
        int i = irow + r;
        float s = sa[r] * scale - slope * (float)(i - j);
        float p = __builtin_amdgcn_exp2f((j <= i) ? s : -1e30f);
        rs[r] += p;
        int rloc = l4 * 4 + r;
        int cbyte = (cb * 16 + l15) * 2;
        *(u16*)((char*)Pw + rloc * 128 + (cbyte ^ ((rloc & 7) << 4))) =
            f32_to_bf16(p);
      }
    }
    bf16x8 pf0 = *(const bf16x8*)((char*)Pw + l15 * 128 +
                                  ((l4 * 16) ^ ((l15 & 7) << 4)));
    bf16x8 pf1 = *(const bf16x8*)((char*)Pw + l15 * 128 +
                                  ((64 + l4 * 16) ^ ((l15 & 7) << 4)));
#pragma unroll
    for (int nb = 0; nb < 8; ++nb) {
      const u16* vp = Vc + (nb * 16 + l15) * 64;
      bf16x8 v0 = *(const bf16x8*)(vp + ((l4 ^ sw) * 8));
      bf16x8 v1 = *(const bf16x8*)(vp + (((4 + l4) ^ sw) * 8));
      O[nb] = __builtin_amdgcn_mfma_f32_16x16x32_bf16(pf0, v0, O[nb], 0, 0, 0);
      O[nb] = __builtin_amdgcn_mfma_f32_16x16x32_bf16(pf1, v1, O[nb], 0, 0, 0);
    }
    __syncthreads();
  }
#pragma unroll
  for (int r = 0; r < 4; ++r) {
    float v = rs[r];
    v += __shfl_xor(v, 1);
    v += __shfl_xor(v, 2);
    v += __shfl_xor(v, 4);
    v += __shfl_xor(v, 8);
    float inv = 1.f / v;
    int i = irow + r;
    u16* op = Oa + ((long)bb * 2048 + i) * 2048 + h * 128;
#pragma unroll
    for (int nb = 0; nb < 8; ++nb) op[nb * 16 + l15] = f32_to_bf16(O[nb][r] * inv);
  }
}

extern "C" void kernel_launch(void* const* d_in, const int* in_sizes, int n_in,
                              void* d_out, int out_size, void* d_ws, size_t ws_size,
                              hipStream_t stream) {
  const float* x = (const float*)d_in[0];
  const float* Wqkv = (const float*)d_in[1];
  const float* bqkv = (const float*)d_in[2];
  const float* Wo = (const float*)d_in[3];
  const float* bo = (const float*)d_in[4];
  float* out = (float*)d_out;

  char* ws = (char*)d_ws;
  u16* xb = (u16*)(ws);
  u16* VTb = (u16*)(ws);  // aliases xb (xb dead after GEMM1)
  u16* WqkvT = (u16*)(ws + 16777216);
  u16* attn_out = (u16*)(ws + 16777216);  // aliases WqkvT (dead after GEMM1)
  u16* WoT = (u16*)(ws + 16777216 + 25165824);
  u16* Qb = (u16*)(ws + 50331648);
  u16* Kb = (u16*)(ws + 67108864);
  u16* Vb = (u16*)(ws + 83886080);

  k_convert<<<8192, 256, 0, stream>>>(x, xb, 8388608 / 4);
  k_transpose_w<<<dim3(192, 64), 256, 0, stream>>>(Wqkv, WqkvT, 2048, 6144);
  k_transpose_w<<<dim3(64, 64), 256, 0, stream>>>(Wo, WoT, 2048, 2048);
  // GEMM1: 128^2 tiles -> 32 x 48 = 1536 blocks (6/CU work, 4 resident/CU)
  k_gemm<0><<<dim3(1536), 256, 0, stream>>>(xb, WqkvT, bqkv, Qb, Kb, Vb,
                                            nullptr, 4096, 6144, 2048);
  k_transpose_v<<<dim3(64, 4, 32), 256, 0, stream>>>(Vb, VTb);
  // attn: 1024 blocks x 4 waves, double-buffered K/V, heavy-first LPT
  k_attn<<<dim3(1024), 256, 0, stream>>>(Qb, Kb, VTb, attn_out);
  // GEMM2: 128^2 tiles -> 32 x 16 = 512 blocks (2/CU work, all resident)
  k_gemm<1><<<dim3(512), 256, 0, stream>>>(attn_out, WoT, bo, nullptr,
                                           nullptr, nullptr, out, 4096, 2048,
                                           2048);
}

// Round 23
// 271.949 us; speedup vs baseline: 2.6790x; 1.0312x over previous
//
#include <hip/hip_runtime.h>

typedef __attribute__((ext_vector_type(4))) float f32x4;
typedef __attribute__((ext_vector_type(8))) __bf16 bf16x8;
typedef unsigned short u16;

#define GAS(p) ((const __attribute__((address_space(1))) void*)(p))
#define LAS(p) ((__attribute__((address_space(3))) void*)(p))

__device__ __forceinline__ u16 f32_to_bf16(float f) {
  unsigned u = __builtin_bit_cast(unsigned, f);
  u += 0x7FFFu + ((u >> 16) & 1u);
  return (u16)(u >> 16);
}

// ---------------- elementwise f32 -> bf16 ----------------
__global__ __launch_bounds__(256) void k_convert(const float* __restrict__ X,
                                                 u16* __restrict__ Y, int n4) {
  int i = blockIdx.x * 256 + threadIdx.x;
  if (i >= n4) return;
  float4 v = ((const float4*)X)[i];
  ushort4 r;
  r.x = f32_to_bf16(v.x); r.y = f32_to_bf16(v.y);
  r.z = f32_to_bf16(v.z); r.w = f32_to_bf16(v.w);
  ((ushort4*)Y)[i] = r;
}

// ---------------- W [K][N] f32 -> WT [N][K] bf16 ----------------
__global__ __launch_bounds__(256) void k_transpose_w(const float* __restrict__ W,
                                                     u16* __restrict__ WT,
                                                     int K, int N) {
  __shared__ float tile[32][33];
  int n0 = blockIdx.x * 32, k0 = blockIdx.y * 32;
  int tx = threadIdx.x & 31, ty = threadIdx.x >> 5;
#pragma unroll
  for (int r = 0; r < 4; ++r)
    tile[ty + r * 8][tx] = W[(long)(k0 + ty + r * 8) * N + n0 + tx];
  __syncthreads();
#pragma unroll
  for (int r = 0; r < 4; ++r)
    WT[(long)(n0 + ty + r * 8) * K + k0 + tx] = f32_to_bf16(tile[tx][ty + r * 8]);
}

// ---------------- V [BH][S][128] bf16 -> VT [BH][128][S] bf16 ----------------
__global__ __launch_bounds__(256) void k_transpose_v(const u16* __restrict__ V,
                                                     u16* __restrict__ VT) {
  __shared__ u16 tile[32][34];
  int s0 = blockIdx.x * 32, d0 = blockIdx.y * 32, bh = blockIdx.z;
  int tx = threadIdx.x & 31, ty = threadIdx.x >> 5;
  const u16* Vb = V + (long)bh * 2048 * 128;
  u16* VTb = VT + (long)bh * 128 * 2048;
#pragma unroll
  for (int r = 0; r < 4; ++r)
    tile[ty + r * 8][tx] = Vb[(long)(s0 + ty + r * 8) * 128 + d0 + tx];
  __syncthreads();
#pragma unroll
  for (int r = 0; r < 4; ++r)
    VTb[(long)(d0 + ty + r * 8) * 2048 + s0 + tx] = tile[tx][ty + r * 8];
}

// ===== 128x128 bf16 GEMM, BK=32, 3 LDS buffers, 4 waves, 3 BLOCKS/CU =====
// SESSION OPTIMUM (reproduced at 271.2 and 272.5 us total). Full lever map
// measured: 3-blk + counted vmcnt(4) beats {1-blk counted (R8: 153.8us),
// 8-phase 1-blk (R11-13: 164-176us), 2-blk bigger wave tiles (R16: 163us),
// 4-blk exposed-drain (R22: 152.9us), 5-blk (R21: spill)}. The two wins
// all session: residency 1->3 (R14, +33%) and conflict-free swizzle (R15).
template <int EPI>
__global__ __launch_bounds__(256, 3) void k_gemm(
    const u16* __restrict__ A, const u16* __restrict__ BT,
    const float* __restrict__ bias,
    u16* __restrict__ Qo, u16* __restrict__ Ko, u16* __restrict__ Vo,
    float* __restrict__ Cout, int M, int N, int K) {
  __shared__ alignas(16) u16 AS[3][128 * 32];  // 3 x 8 KB
  __shared__ alignas(16) u16 BS[3][128 * 32];  // 3 x 8 KB
  const int wave = threadIdx.x >> 6, lane = threadIdx.x & 63;
  const int wr = wave >> 1, wc = wave & 1;
  const int l15 = lane & 15, l4 = lane >> 4;
  // staging: 1KB chunk = 16 rows x 32 cols; lane -> row lane>>2, slot lane&3;
  // source slot pre-XORed with (row>>1)&3 (proven involution: 64B rows ->
  // start-bank (16*row+4*slot)%32; key (row>>1)&3 -> 2 lanes/bank = free).
  const int srow = lane >> 2;
  const int sslot = (lane & 3) ^ ((srow >> 1) & 3);

  const int nwg = gridDim.x;  // 1536 / 512, both % 8 == 0
  const int swz = ((int)blockIdx.x & 7) * (nwg >> 3) + ((int)blockIdx.x >> 3);
  const int mt = M >> 7;
  const int bm = swz % mt, bn = swz / mt;
  const int brow = bm * 128, bcol = bn * 128;
  const int NT = K >> 5;

  const u16* aBase = A + (long)(brow + wave * 16 + srow) * K + sslot * 8;
  const u16* bBase = BT + (long)(bcol + wave * 16 + srow) * K + sslot * 8;
  const long K64 = (long)K * 64;  // 64-row advance

  auto stage = [&](int t, int buf) {  // 4 global_load_lds dwordx4 / thread
    const long t32 = (long)t * 32;
    __builtin_amdgcn_global_load_lds(GAS(aBase + t32),
                                     LAS(&AS[buf][wave * 512]), 16, 0, 0);
    __builtin_amdgcn_global_load_lds(GAS(aBase + t32 + K64),
                                     LAS(&AS[buf][(wave + 4) * 512]), 16, 0, 0);
    __builtin_amdgcn_global_load_lds(GAS(bBase + t32),
                                     LAS(&BS[buf][wave * 512]), 16, 0, 0);
    __builtin_amdgcn_global_load_lds(GAS(bBase + t32 + K64),
                                     LAS(&BS[buf][(wave + 4) * 512]), 16, 0, 0);
  };

  const f32x4 fzero = {0.f, 0.f, 0.f, 0.f};
  f32x4 acc[4][4];
#pragma unroll
  for (int m = 0; m < 4; ++m)
#pragma unroll
    for (int n = 0; n < 4; ++n) acc[m][n] = fzero;

  const int rkey = (l15 >> 1) & 3;  // read-side XOR key: (row>>1)&3 per lane
  auto compute = [&](int buf) {
    const u16* Ac = &AS[buf][0];
    const u16* Bc = &BS[buf][0];
    bf16x8 afr[4], bfr[4];
#pragma unroll
    for (int f = 0; f < 4; ++f) {
      const int Ra = wr * 64 + f * 16 + l15;
      afr[f] = *(const bf16x8*)(Ac + Ra * 32 + ((l4 ^ rkey) * 8));
      const int Rb = wc * 64 + f * 16 + l15;
      bfr[f] = *(const bf16x8*)(Bc + Rb * 32 + ((l4 ^ rkey) * 8));
    }
    __builtin_amdgcn_s_setprio(1);
#pragma unroll
    for (int m = 0; m < 4; ++m)
#pragma unroll
      for (int n = 0; n < 4; ++n)
        acc[m][n] = __builtin_amdgcn_mfma_f32_16x16x32_bf16(afr[m], bfr[n],
                                                            acc[m][n], 0, 0, 0);
    __builtin_amdgcn_s_setprio(0);
  };

  stage(0, 0);
  stage(1, 1);
  int bufc = 0;
  for (int t = 0; t < NT - 1; ++t) {
    asm volatile("s_waitcnt vmcnt(4)" ::: "memory");  // tile t landed; t+1 flying
    __builtin_amdgcn_s_barrier();
    if (t + 2 < NT) {
      int bufn = bufc + 2;
      if (bufn >= 3) bufn -= 3;
      stage(t + 2, bufn);
    }
    compute(bufc);
    ++bufc;
    if (bufc == 3) bufc = 0;
  }
  asm volatile("s_waitcnt vmcnt(0)" ::: "memory");  // last tile
  __builtin_amdgcn_s_barrier();
  compute(bufc);

  if (EPI == 0) {
    // 128-col tiles never straddle the 2048 Q/K/V boundaries
    const int which = bcol >> 11;
    u16* dst = (which == 0) ? Qo : (which == 1) ? Ko : Vo;
    const int cbase = bcol & 2047;
#pragma unroll
    for (int n = 0; n < 4; ++n) {
      const int col = cbase + wc * 64 + n * 16 + l15;
      const int h = col >> 7, d = col & 127;
      const float bv = bias[bcol + wc * 64 + n * 16 + l15];
#pragma unroll
      for (int m = 0; m < 4; ++m) {
#pragma unroll
        for (int r = 0; r < 4; ++r) {
          const int row = brow + wr * 64 + m * 16 + l4 * 4 + r;  // b*2048+s
          const int bb = row >> 11, s = row & 2047;
          dst[(((long)(bb * 16 + h)) * 2048 + s) * 128 + d] =
              f32_to_bf16(acc[m][n][r] + bv);
        }
      }
    }
  } else {
#pragma unroll
    for (int m = 0; m < 4; ++m)
#pragma unroll
      for (int r = 0; r < 4; ++r) {
        const int row = brow + wr * 64 + m * 16 + l4 * 4 + r;
#pragma unroll
        for (int n = 0; n < 4; ++n) {
          const int col = bcol + wc * 64 + n * 16 + l15;
          Cout[(long)row * N + col] = acc[m][n][r] + bias[col];
        }
      }
  }
}

// ---------------- flash attention with ALiBi, causal ----------------
// R7 form, EXACT — best-measured attention (~75 us). Refuted alternatives:
// 8-wave shared staging (R17/R18), single-buffered 4-block residency (R19).
__global__ __launch_bounds__(256, 4) void k_attn(const u16* __restrict__ Q,
                                                 const u16* __restrict__ Kp,
                                                 const u16* __restrict__ VT,
                                                 u16* __restrict__ Oa) {
  __shared__ alignas(16) u16 Kl[2][64 * 128];
  __shared__ alignas(16) u16 Vl[2][128 * 64];
  __shared__ alignas(16) u16 Pl[4][16 * 64];
  const int b = blockIdx.x;
  const int bh = b & 31;
  const int qt = 31 - (b >> 5);  // heavy-first LPT
  const int bb = bh >> 4, h = bh & 15;
  const int wave = threadIdx.x >> 6, lane = threadIdx.x & 63;
  const int l15 = lane & 15, l4 = lane >> 4;
  const int l7 = lane & 7, l8 = lane >> 3;
  const float LOG2E = 1.4426950408889634f;
  const float scale = 0.08838834764831845f * LOG2E;
  const float slope = exp2f(-0.5f * (float)h) * LOG2E;

  const int q0 = qt * 64 + wave * 16;
  const u16* Qb = Q + ((long)bh * 2048 + q0 + l15) * 128;
  bf16x8 qf[4];
#pragma unroll
  for (int kk = 0; kk < 4; ++kk) qf[kk] = *(const bf16x8*)(Qb + kk * 32 + l4 * 8);

  const u16* Kb = Kp + (long)bh * 2048 * 128;
  const u16* VTb = VT + (long)bh * 128 * 2048;

  auto stageK = [&](int jt, int buf) {
#pragma unroll
    for (int g = 0; g < 4; ++g) {
      const int wcc = g * 4 + wave;
      const int row = wcc * 4 + l4;
      const u16* src = Kb + (long)(jt * 64 + row) * 128 + ((l15 ^ (row & 7)) * 8);
      __builtin_amdgcn_global_load_lds(GAS(src), LAS(&Kl[buf][wcc * 512]), 16, 0, 0);
    }
  };
  auto stageV = [&](int jt, int buf) {
#pragma unroll
    for (int g = 0; g < 4; ++g) {
      const int wcc = g * 4 + wave;
      const int d = wcc * 8 + l8;
      const u16* src = VTb + (long)d * 2048 + jt * 64 + ((l7 ^ l8) * 8);
      __builtin_amdgcn_global_load_lds(GAS(src), LAS(&Vl[buf][wcc * 512]), 16, 0, 0);
    }
  };

  float rs[4];
  f32x4 O[8];
  const f32x4 fzero = {0.f, 0.f, 0.f, 0.f};
#pragma unroll
  for (int r = 0; r < 4; ++r) rs[r] = 0.f;
#pragma unroll
  for (int nb = 0; nb < 8; ++nb) O[nb] = fzero;

  u16* Pw = Pl[wave];
  const int irow = q0 + l4 * 4;
  const int sw = l15 & 7;

  stageK(0, 0);
  stageV(0, 0);
  __syncthreads();

  for (int jt = 0; jt <= qt; ++jt) {
    const int cur = jt & 1;
    if (jt < qt) {
      stageK(jt + 1, cur ^ 1);
      stageV(jt + 1, cur ^ 1);
    }
    const u16* Kc = Kl[cur];
    const u16* Vc = Vl[cur];
    const int j0 = jt * 64;
#pragma unroll
    for (int cb = 0; cb < 4; ++cb) {
      f32x4 sa = fzero;
      const u16* kp = Kc + (cb * 16 + l15) * 128;
#pragma unroll
      for (int kk = 0; kk < 4; ++kk) {
        bf16x8 kf = *(const bf16x8*)(kp + (((kk * 4 + l4) ^ sw) * 8));
        sa = __builtin_amdgcn_mfma_f32_16x16x32_bf16(qf[kk], kf, sa, 0, 0, 0);
      }
      const int j = j0 + cb * 16 + l15;
#pragma unroll
      for (int r = 0; r < 4; ++r) {
        int i = irow + r;
        float s = sa[r] * scale - slope * (float)(i - j);
        float p = __builtin_amdgcn_exp2f((j <= i) ? s : -1e30f);
        rs[r] += p;
        int rloc = l4 * 4 + r;
        int cbyte = (cb * 16 + l15) * 2;
        *(u16*)((char*)Pw + rloc * 128 + (cbyte ^ ((rloc & 7) << 4))) =
            f32_to_bf16(p);
      }
    }
    bf16x8 pf0 = *(const bf16x8*)((char*)Pw + l15 * 128 +
                                  ((l4 * 16) ^ ((l15 & 7) << 4)));
    bf16x8 pf1 = *(const bf16x8*)((char*)Pw + l15 * 128 +
                                  ((64 + l4 * 16) ^ ((l15 & 7) << 4)));
#pragma unroll
    for (int nb = 0; nb < 8; ++nb) {
      const u16* vp = Vc + (nb * 16 + l15) * 64;
      bf16x8 v0 = *(const bf16x8*)(vp + ((l4 ^ sw) * 8));
      bf16x8 v1 = *(const bf16x8*)(vp + (((4 + l4) ^ sw) * 8));
      O[nb] = __builtin_amdgcn_mfma_f32_16x16x32_bf16(pf0, v0, O[nb], 0, 0, 0);
      O[nb] = __builtin_amdgcn_mfma_f32_16x16x32_bf16(pf1, v1, O[nb], 0, 0, 0);
    }
    __syncthreads();
  }
#pragma unroll
  for (int r = 0; r < 4; ++r) {
    float v = rs[r];
    v += __shfl_xor(v, 1);
    v += __shfl_xor(v, 2);
    v += __shfl_xor(v, 4);
    v += __shfl_xor(v, 8);
    float inv = 1.f / v;
    int i = irow + r;
    u16* op = Oa + ((long)bb * 2048 + i) * 2048 + h * 128;
#pragma unroll
    for (int nb = 0; nb < 8; ++nb) op[nb * 16 + l15] = f32_to_bf16(O[nb][r] * inv);
  }
}

extern "C" void kernel_launch(void* const* d_in, const int* in_sizes, int n_in,
                              void* d_out, int out_size, void* d_ws, size_t ws_size,
                              hipStream_t stream) {
  const float* x = (const float*)d_in[0];
  const float* Wqkv = (const float*)d_in[1];
  const float* bqkv = (const float*)d_in[2];
  const float* Wo = (const float*)d_in[3];
  const float* bo = (const float*)d_in[4];
  float* out = (float*)d_out;

  char* ws = (char*)d_ws;
  u16* xb = (u16*)(ws);
  u16* VTb = (u16*)(ws);  // aliases xb (xb dead after GEMM1)
  u16* WqkvT = (u16*)(ws + 16777216);
  u16* attn_out = (u16*)(ws + 16777216);  // aliases WqkvT (dead after GEMM1)
  u16* WoT = (u16*)(ws + 16777216 + 25165824);
  u16* Qb = (u16*)(ws + 50331648);
  u16* Kb = (u16*)(ws + 67108864);
  u16* Vb = (u16*)(ws + 83886080);

  k_convert<<<8192, 256, 0, stream>>>(x, xb, 8388608 / 4);
  k_transpose_w<<<dim3(192, 64), 256, 0, stream>>>(Wqkv, WqkvT, 2048, 6144);
  k_transpose_w<<<dim3(64, 64), 256, 0, stream>>>(Wo, WoT, 2048, 2048);
  // GEMM1: 128^2 tiles -> 32 x 48 = 1536 blocks (6/CU work, 3 resident/CU)
  k_gemm<0><<<dim3(1536), 256, 0, stream>>>(xb, WqkvT, bqkv, Qb, Kb, Vb,
                                            nullptr, 4096, 6144, 2048);
  k_transpose_v<<<dim3(64, 4, 32), 256, 0, stream>>>(Vb, VTb);
  // attn: 1024 blocks x 4 waves, double-buffered K/V, heavy-first LPT
  k_attn<<<dim3(1024), 256, 0, stream>>>(Qb, Kb, VTb, attn_out);
  // GEMM2: 128^2 tiles -> 32 x 16 = 512 blocks (2/CU work, all resident)
  k_gemm<1><<<dim3(512), 256, 0, stream>>>(attn_out, WoT, bo, nullptr,
                                           nullptr, nullptr, out, 4096, 2048,
                                           2048);
}